// Round 1
// baseline (482.767 us; speedup 1.0000x reference)
//
#include <hip/hip_runtime.h>

// ---------------- common helpers ----------------
#define D_MODEL 1024
#define D_STATE 16
#define D_CONV 4
#define D_INNER 2048
#define DT_RANK 64
#define BATCH 2
#define SEQ 2048
#define NROWS (BATCH * SEQ)   // 4096

__device__ __forceinline__ unsigned short f2b(float f) {
    union { float f; unsigned u; } v; v.f = f;
    unsigned r = v.u + 0x7fffu + ((v.u >> 16) & 1u);
    return (unsigned short)(r >> 16);
}
__device__ __forceinline__ float sigmoidf_(float x) { return 1.f / (1.f + __expf(-x)); }

// ---------------- f32 -> bf16 conversion (8 elems/thread) ----------------
__global__ void cvt_kernel(const float* __restrict__ in, unsigned short* __restrict__ out, int n8) {
    int i = blockIdx.x * 256 + threadIdx.x;
    if (i >= n8) return;
    const float4* p = (const float4*)in + (size_t)i * 2;
    float4 a = p[0], b = p[1];
    uint4 o;
    o.x = (unsigned)f2b(a.x) | ((unsigned)f2b(a.y) << 16);
    o.y = (unsigned)f2b(a.z) | ((unsigned)f2b(a.w) << 16);
    o.z = (unsigned)f2b(b.x) | ((unsigned)f2b(b.y) << 16);
    o.w = (unsigned)f2b(b.z) | ((unsigned)f2b(b.w) << 16);
    ((uint4*)out)[i] = o;
}

// ---------------- MFMA GEMM template: C[M,N] = A[M,K] * W[N,K]^T ----------------
// bf16 inputs (ushort storage), f32 output. EPI: 0 = plain, 1 = softplus(acc + bias[col])
typedef short bf16x8 __attribute__((ext_vector_type(8)));
typedef float f32x4 __attribute__((ext_vector_type(4)));

#define BM 128
#define BN 128
#define BK 32
#define LPAD 40   // LDS row stride in elements (padded: 80B -> conflict-free-ish)

template<int EPI>
__global__ __launch_bounds__(256, 2)
void gemm_bt_kernel(const unsigned short* __restrict__ A, int lda,
                    const unsigned short* __restrict__ W, int ldw,
                    float* __restrict__ C, int ldc,
                    int M, int N, int K,
                    const float* __restrict__ bias)
{
    __shared__ unsigned short As[BM * LPAD];
    __shared__ unsigned short Ws[BN * LPAD];
    int tid  = threadIdx.x;
    int lane = tid & 63;
    int wid  = tid >> 6;
    int wr = wid >> 1, wc = wid & 1;
    int bm = blockIdx.y * BM;
    int bn = blockIdx.x * BN;

    f32x4 acc[4][4] = {};

    int srow = tid >> 2;          // 0..63
    int sq   = (tid & 3) * 8;     // k element offset: 0,8,16,24

    int steps = K / BK;
    for (int kt = 0; kt < steps; ++kt) {
        int k0 = kt * BK;
        __syncthreads();
#pragma unroll
        for (int rr = 0; rr < 2; ++rr) {
            int r = srow + rr * 64;
            int gm = bm + r;
            uint4 va = {0, 0, 0, 0};
            if (gm < M) va = *(const uint4*)(A + (size_t)gm * lda + k0 + sq);
            *(uint4*)(As + r * LPAD + sq) = va;
            int gn = bn + r;
            uint4 vw = {0, 0, 0, 0};
            if (gn < N) vw = *(const uint4*)(W + (size_t)gn * ldw + k0 + sq);
            *(uint4*)(Ws + r * LPAD + sq) = vw;
        }
        __syncthreads();

        int frow = lane & 15;
        int fk   = (lane >> 4) * 8;
        bf16x8 af[4], bfv[4];
#pragma unroll
        for (int m = 0; m < 4; ++m)
            af[m] = *(const bf16x8*)(As + (wr * 64 + m * 16 + frow) * LPAD + fk);
#pragma unroll
        for (int n = 0; n < 4; ++n)
            bfv[n] = *(const bf16x8*)(Ws + (wc * 64 + n * 16 + frow) * LPAD + fk);
#pragma unroll
        for (int m = 0; m < 4; ++m)
#pragma unroll
            for (int n = 0; n < 4; ++n)
                acc[m][n] = __builtin_amdgcn_mfma_f32_16x16x32_bf16(af[m], bfv[n], acc[m][n], 0, 0, 0);
    }

    int orow0 = bm + wr * 64 + (lane >> 4) * 4;
    int ocol0 = bn + wc * 64 + (lane & 15);
#pragma unroll
    for (int m = 0; m < 4; ++m) {
#pragma unroll
        for (int n = 0; n < 4; ++n) {
            int col = ocol0 + n * 16;
            if (col >= N) continue;
#pragma unroll
            for (int i = 0; i < 4; ++i) {
                int row = orow0 + m * 16 + i;
                if (row >= M) continue;
                float v = acc[m][n][i];
                if (EPI == 1) {
                    v += bias[col];
                    v = (v > 20.f) ? v : log1pf(__expf(v));
                }
                C[(size_t)row * ldc + col] = v;
            }
        }
    }
}

// ---------------- causal depthwise conv (width 4) + silu; writes f32 and bf16 ----------------
__global__ __launch_bounds__(256)
void conv_silu_kernel(const float* __restrict__ xz,      // [NROWS,4096], xr = cols [0,2048)
                      const float* __restrict__ cw,       // [2048,4]
                      const float* __restrict__ cb,       // [2048]
                      float* __restrict__ xc,             // [NROWS,2048]
                      unsigned short* __restrict__ xcb)   // bf16 copy
{
    int idx = blockIdx.x * 256 + threadIdx.x;   // over NROWS*2048
    int d = idx & 2047;
    int rl = idx >> 11;
    int l = rl & 2047;
    int b = rl >> 11;
    float w0 = cw[d * 4 + 0], w1 = cw[d * 4 + 1], w2 = cw[d * 4 + 2], w3 = cw[d * 4 + 3];
    const float* base = xz + (size_t)(b * SEQ) * 4096 + d;
    float acc = cb[d];
    if (l >= 3) acc += base[(size_t)(l - 3) * 4096] * w0;
    if (l >= 2) acc += base[(size_t)(l - 2) * 4096] * w1;
    if (l >= 1) acc += base[(size_t)(l - 1) * 4096] * w2;
    acc += base[(size_t)l * 4096] * w3;
    float v = acc * sigmoidf_(acc);
    xc[idx] = v;
    xcb[idx] = f2b(v);
}

// ---------------- chunked SSM scan ----------------
#define CL 64      // chunk length
#define NCH 32     // chunks per batch (CL*NCH == SEQ)

// pass A: per-chunk partials. P = prod(dA), Q = local final h (h0=0)
__global__ __launch_bounds__(256)
void scan_partial_kernel(const float* __restrict__ dt, int dt_stride,
                         const float* __restrict__ xc,
                         const float* __restrict__ xdb,     // [NROWS,96]
                         const float* __restrict__ A_log,   // [2048,16]
                         float* __restrict__ P, float* __restrict__ Q)
{
    int bx = blockIdx.x;              // 512 blocks: b(1b) | c(5b) | dblk(3b)
    int dblk = bx & 7;
    int c = (bx >> 3) & 31;
    int b = bx >> 8;
    int d = dblk * 256 + threadIdx.x;
    int ch = b * D_INNER + d;
    int l0 = c * CL;

    float Av[D_STATE];
#pragma unroll
    for (int s = 0; s < D_STATE; ++s) Av[s] = -__expf(A_log[d * D_STATE + s]);

    __shared__ float Bs[CL][D_STATE];
    for (int i = threadIdx.x; i < CL * D_STATE; i += 256) {
        int ll = i >> 4, s = i & 15;
        Bs[ll][s] = xdb[(size_t)(b * SEQ + l0 + ll) * 96 + 64 + s];
    }
    __syncthreads();

    float h[D_STATE], Pp[D_STATE];
#pragma unroll
    for (int s = 0; s < D_STATE; ++s) { h[s] = 0.f; Pp[s] = 1.f; }

    for (int li = 0; li < CL; ++li) {
        size_t row = (size_t)(b * SEQ + l0 + li);
        float dtv = dt[row * dt_stride + d];
        float xcv = xc[row * D_INNER + d];
        float bx_ = dtv * xcv;
#pragma unroll
        for (int s = 0; s < D_STATE; ++s) {
            float da = __expf(dtv * Av[s]);
            h[s] = da * h[s] + bx_ * Bs[li][s];
            Pp[s] *= da;
        }
    }
#pragma unroll
    for (int s = 0; s < D_STATE; ++s) {
        size_t o = ((size_t)(c * D_STATE + s) << 12) + ch;
        P[o] = Pp[s];
        Q[o] = h[s];
    }
}

// pass B: sequential combine across chunks -> h_start per chunk
__global__ void scan_combine_kernel(const float* __restrict__ P, const float* __restrict__ Q,
                                    float* __restrict__ Hs)
{
    int ch = blockIdx.x * 256 + threadIdx.x;   // 0..4095
    float h[D_STATE];
#pragma unroll
    for (int s = 0; s < D_STATE; ++s) h[s] = 0.f;
    for (int c = 0; c < NCH; ++c) {
#pragma unroll
        for (int s = 0; s < D_STATE; ++s) {
            size_t o = ((size_t)(c * D_STATE + s) << 12) + ch;
            Hs[o] = h[s];
            h[s] = P[o] * h[s] + Q[o];
        }
    }
}

// pass C: re-scan with correct h0; fuse skip (D), gate (silu(z)); emit y bf16
__global__ __launch_bounds__(256)
void scan_final_kernel(const float* __restrict__ dt, int dt_stride,
                       const float* __restrict__ xc,
                       const float* __restrict__ xdb,
                       const float* __restrict__ A_log,
                       const float* __restrict__ Hs,
                       const float* __restrict__ Dp,
                       const float* __restrict__ xz,     // z = cols [2048,4096)
                       unsigned short* __restrict__ yb)  // [NROWS,2048] bf16
{
    int bx = blockIdx.x;
    int dblk = bx & 7;
    int c = (bx >> 3) & 31;
    int b = bx >> 8;
    int d = dblk * 256 + threadIdx.x;
    int ch = b * D_INNER + d;
    int l0 = c * CL;

    float Av[D_STATE];
#pragma unroll
    for (int s = 0; s < D_STATE; ++s) Av[s] = -__expf(A_log[d * D_STATE + s]);

    __shared__ float BCs[CL][32];
    for (int i = threadIdx.x; i < CL * 32; i += 256) {
        int ll = i >> 5, s2 = i & 31;
        BCs[ll][s2] = xdb[(size_t)(b * SEQ + l0 + ll) * 96 + 64 + s2];
    }
    __syncthreads();

    float h[D_STATE];
#pragma unroll
    for (int s = 0; s < D_STATE; ++s) h[s] = Hs[((size_t)(c * D_STATE + s) << 12) + ch];
    float Dv = Dp[d];

    for (int li = 0; li < CL; ++li) {
        size_t row = (size_t)(b * SEQ + l0 + li);
        float dtv = dt[row * dt_stride + d];
        float xcv = xc[row * D_INNER + d];
        float bx_ = dtv * xcv;
        float y = 0.f;
#pragma unroll
        for (int s = 0; s < D_STATE; ++s) {
            float da = __expf(dtv * Av[s]);
            h[s] = da * h[s] + bx_ * BCs[li][s];
            y += h[s] * BCs[li][16 + s];
        }
        float zv = xz[row * 4096 + D_INNER + d];
        float yo = (y + xcv * Dv) * (zv * sigmoidf_(zv));
        yb[row * D_INNER + d] = f2b(yo);
    }
}

// ---------------- residual + LayerNorm ----------------
__global__ __launch_bounds__(256)
void ln_kernel(const float* __restrict__ mm, const float* __restrict__ x,
               const float* __restrict__ w, const float* __restrict__ bns,
               float* __restrict__ out)
{
    int row = blockIdx.x;
    int tid = threadIdx.x;
    const float* pm = mm + (size_t)row * D_MODEL;
    const float* px = x + (size_t)row * D_MODEL;
    float v[4];
    float sum = 0.f, ss = 0.f;
#pragma unroll
    for (int i = 0; i < 4; ++i) {
        float t = pm[tid + i * 256] + px[tid + i * 256];
        v[i] = t; sum += t; ss += t * t;
    }
#pragma unroll
    for (int off = 32; off > 0; off >>= 1) {
        sum += __shfl_down(sum, off);
        ss  += __shfl_down(ss, off);
    }
    __shared__ float s1[4], s2[4];
    int wv = tid >> 6, lane = tid & 63;
    if (lane == 0) { s1[wv] = sum; s2[wv] = ss; }
    __syncthreads();
    sum = s1[0] + s1[1] + s1[2] + s1[3];
    ss  = s2[0] + s2[1] + s2[2] + s2[3];
    float mu  = sum * (1.f / D_MODEL);
    float var = ss * (1.f / D_MODEL) - mu * mu;
    float inv = rsqrtf(var + 1e-5f);
#pragma unroll
    for (int i = 0; i < 4; ++i) {
        int cidx = tid + i * 256;
        out[(size_t)row * D_MODEL + cidx] = (v[i] - mu) * inv * w[cidx] + bns[cidx];
    }
}

// ---------------- host launch ----------------
extern "C" void kernel_launch(void* const* d_in, const int* in_sizes, int n_in,
                              void* d_out, int out_size, void* d_ws, size_t ws_size,
                              hipStream_t stream)
{
    const float* x    = (const float*)d_in[0];
    const float* w1   = (const float*)d_in[1];
    const float* cw   = (const float*)d_in[2];
    const float* cb   = (const float*)d_in[3];
    const float* xpw  = (const float*)d_in[4];
    const float* dtw  = (const float*)d_in[5];
    const float* dtb  = (const float*)d_in[6];
    const float* Alog = (const float*)d_in[7];
    const float* Dp   = (const float*)d_in[8];
    const float* w4   = (const float*)d_in[9];
    const float* lnw  = (const float*)d_in[10];
    const float* lnb  = (const float*)d_in[11];
    float* out = (float*)d_out;

    char* ws = (char*)d_ws;
    size_t off = 0;
    auto alloc = [&](size_t bytes) { size_t o = off; off = (off + bytes + 255) & ~(size_t)255; return o; };

    float* xz   = (float*)(ws + alloc((size_t)NROWS * 4096 * 4));   // 67MB; dt aliases cols [0,2048)
    float* xc   = (float*)(ws + alloc((size_t)NROWS * 2048 * 4));   // 33.5MB; out_mm aliases
    float* xdb  = (float*)(ws + alloc((size_t)NROWS * 96 * 4));
    float* P    = (float*)(ws + alloc((size_t)NCH * 16 * 4096 * 4));
    float* Q    = (float*)(ws + alloc((size_t)NCH * 16 * 4096 * 4));
    float* Hs   = (float*)(ws + alloc((size_t)NCH * 16 * 4096 * 4));
    unsigned short* xb   = (unsigned short*)(ws + alloc((size_t)NROWS * 1024 * 2));
    unsigned short* w1b  = (unsigned short*)(ws + alloc((size_t)4096 * 1024 * 2));
    unsigned short* xpwb = (unsigned short*)(ws + alloc((size_t)96 * 2048 * 2));
    unsigned short* dtwb = (unsigned short*)(ws + alloc((size_t)2048 * 64 * 2));
    unsigned short* w4b  = (unsigned short*)(ws + alloc((size_t)1024 * 2048 * 2));
    unsigned short* xcb  = (unsigned short*)(ws + alloc((size_t)NROWS * 2048 * 2)); // yb aliases
    unsigned short* xdbb = (unsigned short*)(ws + alloc((size_t)NROWS * 96 * 2));

    float* dtp = xz;                 // dt written with stride 4096 over xr region
    float* out_mm = xc;              // written after pass C consumed xc... (G4 after scan)
    unsigned short* yb = xcb;        // bf16 gated y, written after xcb consumed by G2

    // 1-5: conversions
    cvt_kernel<<<(NROWS * 1024 / 8 + 255) / 256, 256, 0, stream>>>(x, xb, NROWS * 1024 / 8);
    cvt_kernel<<<(4096 * 1024 / 8 + 255) / 256, 256, 0, stream>>>(w1, w1b, 4096 * 1024 / 8);
    cvt_kernel<<<(96 * 2048 / 8 + 255) / 256, 256, 0, stream>>>(xpw, xpwb, 96 * 2048 / 8);
    cvt_kernel<<<(2048 * 64 / 8 + 255) / 256, 256, 0, stream>>>(dtw, dtwb, 2048 * 64 / 8);
    cvt_kernel<<<(1024 * 2048 / 8 + 255) / 256, 256, 0, stream>>>(w4, w4b, 1024 * 2048 / 8);

    // 6: in_proj  xz[4096,4096] = xb[4096,1024] @ w1b[4096,1024]^T
    gemm_bt_kernel<0><<<dim3(32, 32), 256, 0, stream>>>(xb, 1024, w1b, 1024, xz, 4096,
                                                        NROWS, 4096, 1024, nullptr);
    // 7: conv + silu
    conv_silu_kernel<<<NROWS * 2048 / 256, 256, 0, stream>>>(xz, cw, cb, xc, xcb);
    // 8: x_proj  xdb[4096,96] = xcb @ xpwb^T
    gemm_bt_kernel<0><<<dim3(1, 32), 256, 0, stream>>>(xcb, 2048, xpwb, 2048, xdb, 96,
                                                       NROWS, 96, 2048, nullptr);
    // 9: xdb -> bf16
    cvt_kernel<<<(NROWS * 96 / 8 + 255) / 256, 256, 0, stream>>>(xdb, xdbb, NROWS * 96 / 8);
    // 10: dt_proj + softplus  dt[4096,2048] (stride 4096, aliases xz xr-half)
    gemm_bt_kernel<1><<<dim3(16, 32), 256, 0, stream>>>(xdbb, 96, dtwb, 64, dtp, 4096,
                                                        NROWS, 2048, 64, dtb);
    // 11-13: chunked scan
    scan_partial_kernel<<<512, 256, 0, stream>>>(dtp, 4096, xc, xdb, Alog, P, Q);
    scan_combine_kernel<<<16, 256, 0, stream>>>(P, Q, Hs);
    scan_final_kernel<<<512, 256, 0, stream>>>(dtp, 4096, xc, xdb, Alog, Hs, Dp, xz, yb);
    // 14: out_proj  out_mm[4096,1024] = yb @ w4b^T   (out_mm aliases xc, dead now)
    gemm_bt_kernel<0><<<dim3(8, 32), 256, 0, stream>>>(yb, 2048, w4b, 2048, out_mm, 1024,
                                                       NROWS, 1024, 2048, nullptr);
    // 15: residual + LayerNorm
    ln_kernel<<<NROWS, 256, 0, stream>>>(out_mm, x, lnw, lnb, out);
}

// Round 2
// 397.376 us; speedup vs baseline: 1.2149x; 1.2149x over previous
//
#include <hip/hip_runtime.h>

// ---------------- common helpers ----------------
#define D_MODEL 1024
#define D_STATE 16
#define D_CONV 4
#define D_INNER 2048
#define DT_RANK 64
#define BATCH 2
#define SEQ 2048
#define NROWS (BATCH * SEQ)   // 4096

__device__ __forceinline__ unsigned short f2b(float f) {
    union { float f; unsigned u; } v; v.f = f;
    unsigned r = v.u + 0x7fffu + ((v.u >> 16) & 1u);
    return (unsigned short)(r >> 16);
}
__device__ __forceinline__ float sigmoidf_(float x) { return 1.f / (1.f + __expf(-x)); }

// async global->LDS, 16B per lane. LDS dest must be wave-uniform base.
__device__ __forceinline__ void gld_lds16(const unsigned short* g, unsigned short* l) {
    __builtin_amdgcn_global_load_lds(
        (const __attribute__((address_space(1))) void*)g,
        (__attribute__((address_space(3))) void*)l, 16, 0, 0);
}

// ---------------- f32 -> bf16 conversion (8 elems/thread) ----------------
__global__ void cvt_kernel(const float* __restrict__ in, unsigned short* __restrict__ out, int n8) {
    int i = blockIdx.x * 256 + threadIdx.x;
    if (i >= n8) return;
    const float4* p = (const float4*)in + (size_t)i * 2;
    float4 a = p[0], b = p[1];
    uint4 o;
    o.x = (unsigned)f2b(a.x) | ((unsigned)f2b(a.y) << 16);
    o.y = (unsigned)f2b(a.z) | ((unsigned)f2b(a.w) << 16);
    o.z = (unsigned)f2b(b.x) | ((unsigned)f2b(b.y) << 16);
    o.w = (unsigned)f2b(b.z) | ((unsigned)f2b(b.w) << 16);
    ((uint4*)out)[i] = o;
}

// ---------------- MFMA GEMM, m97 structure: C = A[M,K] * W[N,K]^T ----------------
// 128x128 tile, BK=64, 4 waves (2x2), global_load_lds width-16 staging, linear LDS.
// EPI: 0 = plain, 1 = softplus(acc + bias[col]).
// Split-K via blockIdx.z: computes K range [z*ksteps*64, ...), writes C + z*M*ldc.
typedef short bf16x8 __attribute__((ext_vector_type(8)));
typedef float f32x4 __attribute__((ext_vector_type(4)));

template<int EPI>
__global__ __launch_bounds__(256)
void gemm_gl_kernel(const unsigned short* __restrict__ A, int lda,
                    const unsigned short* __restrict__ W, int ldw,
                    float* __restrict__ C, int ldc,
                    int M, int N, int ksteps,
                    const float* __restrict__ bias)
{
    __shared__ __attribute__((aligned(16))) unsigned short As[128 * 64];
    __shared__ __attribute__((aligned(16))) unsigned short Ws[128 * 64];
    int tid = threadIdx.x;
    int lane = tid & 63, wid = tid >> 6;
    int wr = wid >> 1, wc = wid & 1;
    int bm = blockIdx.y * 128, bn = blockIdx.x * 128;
    int kbeg = blockIdx.z * ksteps * 64;
    C += (size_t)blockIdx.z * (size_t)M * ldc;

    int sr = lane >> 3;          // row within 8-row chunk
    int sk = (lane & 7) * 8;     // k-element offset within 64
    const unsigned short* Abase = A + (size_t)bm * lda + kbeg + sk;
    const unsigned short* Wbase = W + (size_t)bn * ldw + kbeg + sk;

    f32x4 acc[4][4] = {};
    int frow = lane & 15;

    for (int kt = 0; kt < ksteps; ++kt) {
        int k0 = kt * 64;
        __syncthreads();
#pragma unroll
        for (int j = 0; j < 4; ++j) {
            int c = wid * 4 + j;     // 16 chunks of 8 rows; wave-uniform
            gld_lds16(Abase + (size_t)(c * 8 + sr) * lda + k0, As + c * 512);
            gld_lds16(Wbase + (size_t)(c * 8 + sr) * ldw + k0, Ws + c * 512);
        }
        __syncthreads();   // compiler emits vmcnt(0) drain before barrier

#pragma unroll
        for (int ks = 0; ks < 2; ++ks) {
            int fk = ks * 32 + (lane >> 4) * 8;
            bf16x8 af[4], bfv[4];
#pragma unroll
            for (int m = 0; m < 4; ++m)
                af[m] = *(const bf16x8*)(As + (wr * 64 + m * 16 + frow) * 64 + fk);
#pragma unroll
            for (int n = 0; n < 4; ++n)
                bfv[n] = *(const bf16x8*)(Ws + (wc * 64 + n * 16 + frow) * 64 + fk);
#pragma unroll
            for (int m = 0; m < 4; ++m)
#pragma unroll
                for (int n = 0; n < 4; ++n)
                    acc[m][n] = __builtin_amdgcn_mfma_f32_16x16x32_bf16(af[m], bfv[n], acc[m][n], 0, 0, 0);
        }
    }

    int orow0 = bm + wr * 64 + (lane >> 4) * 4;
    int ocol0 = bn + wc * 64 + frow;
#pragma unroll
    for (int m = 0; m < 4; ++m) {
#pragma unroll
        for (int n = 0; n < 4; ++n) {
            int col = ocol0 + n * 16;
            if (col >= N) continue;
            float bv = (EPI == 1) ? bias[col] : 0.f;
#pragma unroll
            for (int i = 0; i < 4; ++i) {
                int row = orow0 + m * 16 + i;
                if (row >= M) continue;
                float v = acc[m][n][i];
                if (EPI == 1) {
                    v += bv;
                    v = (v > 20.f) ? v : log1pf(__expf(v));
                }
                C[(size_t)row * ldc + col] = v;
            }
        }
    }
}

// ---------------- split-K reduce for x_proj; fuses bf16 cvt ----------------
__global__ __launch_bounds__(256)
void xproj_reduce_kernel(const float* __restrict__ Cp, float* __restrict__ xdb,
                         unsigned short* __restrict__ xdbb)
{
    int idx = blockIdx.x * 256 + threadIdx.x;   // over NROWS*96
    if (idx >= NROWS * 96) return;
    float s = 0.f;
#pragma unroll
    for (int z = 0; z < 8; ++z) s += Cp[(size_t)z * NROWS * 96 + idx];
    xdb[idx] = s;
    xdbb[idx] = f2b(s);
}

// ---------------- causal depthwise conv (width 4) + silu; writes f32 and bf16 ----------------
__global__ __launch_bounds__(256)
void conv_silu_kernel(const float* __restrict__ xz,      // [NROWS,4096], xr = cols [0,2048)
                      const float* __restrict__ cw,       // [2048,4]
                      const float* __restrict__ cb,       // [2048]
                      float* __restrict__ xc,             // [NROWS,2048]
                      unsigned short* __restrict__ xcb)   // bf16 copy
{
    int idx = blockIdx.x * 256 + threadIdx.x;   // over NROWS*2048
    int d = idx & 2047;
    int rl = idx >> 11;
    int l = rl & 2047;
    int b = rl >> 11;
    float w0 = cw[d * 4 + 0], w1 = cw[d * 4 + 1], w2 = cw[d * 4 + 2], w3 = cw[d * 4 + 3];
    const float* base = xz + (size_t)(b * SEQ) * 4096 + d;
    float acc = cb[d];
    if (l >= 3) acc += base[(size_t)(l - 3) * 4096] * w0;
    if (l >= 2) acc += base[(size_t)(l - 2) * 4096] * w1;
    if (l >= 1) acc += base[(size_t)(l - 1) * 4096] * w2;
    acc += base[(size_t)l * 4096] * w3;
    float v = acc * sigmoidf_(acc);
    xc[idx] = v;
    xcb[idx] = f2b(v);
}

// ---------------- chunked SSM scan ----------------
#define CL 64      // chunk length
#define NCH 32     // chunks per batch (CL*NCH == SEQ)

__global__ __launch_bounds__(256)
void scan_partial_kernel(const float* __restrict__ dt, int dt_stride,
                         const float* __restrict__ xc,
                         const float* __restrict__ xdb,     // [NROWS,96]
                         const float* __restrict__ A_log,   // [2048,16]
                         float* __restrict__ P, float* __restrict__ Q)
{
    int bx = blockIdx.x;              // 512 blocks: b(1b) | c(5b) | dblk(3b)
    int dblk = bx & 7;
    int c = (bx >> 3) & 31;
    int b = bx >> 8;
    int d = dblk * 256 + threadIdx.x;
    int ch = b * D_INNER + d;
    int l0 = c * CL;

    float Av[D_STATE];
#pragma unroll
    for (int s = 0; s < D_STATE; ++s) Av[s] = -__expf(A_log[d * D_STATE + s]);

    __shared__ float Bs[CL][D_STATE];
    for (int i = threadIdx.x; i < CL * D_STATE; i += 256) {
        int ll = i >> 4, s = i & 15;
        Bs[ll][s] = xdb[(size_t)(b * SEQ + l0 + ll) * 96 + 64 + s];
    }
    __syncthreads();

    float h[D_STATE], Pp[D_STATE];
#pragma unroll
    for (int s = 0; s < D_STATE; ++s) { h[s] = 0.f; Pp[s] = 1.f; }

    for (int li = 0; li < CL; ++li) {
        size_t row = (size_t)(b * SEQ + l0 + li);
        float dtv = dt[row * dt_stride + d];
        float xcv = xc[row * D_INNER + d];
        float bx_ = dtv * xcv;
#pragma unroll
        for (int s = 0; s < D_STATE; ++s) {
            float da = __expf(dtv * Av[s]);
            h[s] = da * h[s] + bx_ * Bs[li][s];
            Pp[s] *= da;
        }
    }
#pragma unroll
    for (int s = 0; s < D_STATE; ++s) {
        size_t o = ((size_t)(c * D_STATE + s) << 12) + ch;
        P[o] = Pp[s];
        Q[o] = h[s];
    }
}

__global__ void scan_combine_kernel(const float* __restrict__ P, const float* __restrict__ Q,
                                    float* __restrict__ Hs)
{
    int ch = blockIdx.x * 256 + threadIdx.x;   // 0..4095
    float h[D_STATE];
#pragma unroll
    for (int s = 0; s < D_STATE; ++s) h[s] = 0.f;
    for (int c = 0; c < NCH; ++c) {
#pragma unroll
        for (int s = 0; s < D_STATE; ++s) {
            size_t o = ((size_t)(c * D_STATE + s) << 12) + ch;
            Hs[o] = h[s];
            h[s] = P[o] * h[s] + Q[o];
        }
    }
}

__global__ __launch_bounds__(256)
void scan_final_kernel(const float* __restrict__ dt, int dt_stride,
                       const float* __restrict__ xc,
                       const float* __restrict__ xdb,
                       const float* __restrict__ A_log,
                       const float* __restrict__ Hs,
                       const float* __restrict__ Dp,
                       const float* __restrict__ xz,     // z = cols [2048,4096)
                       unsigned short* __restrict__ yb)  // [NROWS,2048] bf16
{
    int bx = blockIdx.x;
    int dblk = bx & 7;
    int c = (bx >> 3) & 31;
    int b = bx >> 8;
    int d = dblk * 256 + threadIdx.x;
    int ch = b * D_INNER + d;
    int l0 = c * CL;

    float Av[D_STATE];
#pragma unroll
    for (int s = 0; s < D_STATE; ++s) Av[s] = -__expf(A_log[d * D_STATE + s]);

    __shared__ float BCs[CL][32];
    for (int i = threadIdx.x; i < CL * 32; i += 256) {
        int ll = i >> 5, s2 = i & 31;
        BCs[ll][s2] = xdb[(size_t)(b * SEQ + l0 + ll) * 96 + 64 + s2];
    }
    __syncthreads();

    float h[D_STATE];
#pragma unroll
    for (int s = 0; s < D_STATE; ++s) h[s] = Hs[((size_t)(c * D_STATE + s) << 12) + ch];
    float Dv = Dp[d];

    for (int li = 0; li < CL; ++li) {
        size_t row = (size_t)(b * SEQ + l0 + li);
        float dtv = dt[row * dt_stride + d];
        float xcv = xc[row * D_INNER + d];
        float bx_ = dtv * xcv;
        float y = 0.f;
#pragma unroll
        for (int s = 0; s < D_STATE; ++s) {
            float da = __expf(dtv * Av[s]);
            h[s] = da * h[s] + bx_ * BCs[li][s];
            y += h[s] * BCs[li][16 + s];
        }
        float zv = xz[row * 4096 + D_INNER + d];
        float yo = (y + xcv * Dv) * (zv * sigmoidf_(zv));
        yb[row * D_INNER + d] = f2b(yo);
    }
}

// ---------------- residual + LayerNorm ----------------
__global__ __launch_bounds__(256)
void ln_kernel(const float* __restrict__ mm, const float* __restrict__ x,
               const float* __restrict__ w, const float* __restrict__ bns,
               float* __restrict__ out)
{
    int row = blockIdx.x;
    int tid = threadIdx.x;
    const float* pm = mm + (size_t)row * D_MODEL;
    const float* px = x + (size_t)row * D_MODEL;
    float v[4];
    float sum = 0.f, ss = 0.f;
#pragma unroll
    for (int i = 0; i < 4; ++i) {
        float t = pm[tid + i * 256] + px[tid + i * 256];
        v[i] = t; sum += t; ss += t * t;
    }
#pragma unroll
    for (int off = 32; off > 0; off >>= 1) {
        sum += __shfl_down(sum, off);
        ss  += __shfl_down(ss, off);
    }
    __shared__ float s1[4], s2[4];
    int wv = tid >> 6, lane = tid & 63;
    if (lane == 0) { s1[wv] = sum; s2[wv] = ss; }
    __syncthreads();
    sum = s1[0] + s1[1] + s1[2] + s1[3];
    ss  = s2[0] + s2[1] + s2[2] + s2[3];
    float mu  = sum * (1.f / D_MODEL);
    float var = ss * (1.f / D_MODEL) - mu * mu;
    float inv = rsqrtf(var + 1e-5f);
#pragma unroll
    for (int i = 0; i < 4; ++i) {
        int cidx = tid + i * 256;
        out[(size_t)row * D_MODEL + cidx] = (v[i] - mu) * inv * w[cidx] + bns[cidx];
    }
}

// ---------------- host launch ----------------
extern "C" void kernel_launch(void* const* d_in, const int* in_sizes, int n_in,
                              void* d_out, int out_size, void* d_ws, size_t ws_size,
                              hipStream_t stream)
{
    const float* x    = (const float*)d_in[0];
    const float* w1   = (const float*)d_in[1];
    const float* cw   = (const float*)d_in[2];
    const float* cb   = (const float*)d_in[3];
    const float* xpw  = (const float*)d_in[4];
    const float* dtw  = (const float*)d_in[5];
    const float* dtb  = (const float*)d_in[6];
    const float* Alog = (const float*)d_in[7];
    const float* Dp   = (const float*)d_in[8];
    const float* w4   = (const float*)d_in[9];
    const float* lnw  = (const float*)d_in[10];
    const float* lnb  = (const float*)d_in[11];
    float* out = (float*)d_out;

    char* ws = (char*)d_ws;
    size_t off = 0;
    auto alloc = [&](size_t bytes) { size_t o = off; off = (off + bytes + 255) & ~(size_t)255; return o; };

    float* xz   = (float*)(ws + alloc((size_t)NROWS * 4096 * 4));   // 67MB; dt aliases cols [0,2048)
    float* xc   = (float*)(ws + alloc((size_t)NROWS * 2048 * 4));   // 33.5MB; out_mm aliases
    float* xdb  = (float*)(ws + alloc((size_t)NROWS * 96 * 4));
    float* P    = (float*)(ws + alloc((size_t)NCH * 16 * 4096 * 4));
    float* Q    = (float*)(ws + alloc((size_t)NCH * 16 * 4096 * 4));
    float* Hs   = (float*)(ws + alloc((size_t)NCH * 16 * 4096 * 4));
    unsigned short* xb   = (unsigned short*)(ws + alloc((size_t)NROWS * 1024 * 2));
    unsigned short* w1b  = (unsigned short*)(ws + alloc((size_t)4096 * 1024 * 2));
    unsigned short* xpwb = (unsigned short*)(ws + alloc((size_t)128 * 2048 * 2)); // padded 96->128 rows
    unsigned short* dtwb = (unsigned short*)(ws + alloc((size_t)2048 * 64 * 2));
    unsigned short* w4b  = (unsigned short*)(ws + alloc((size_t)1024 * 2048 * 2));
    unsigned short* xcb  = (unsigned short*)(ws + alloc((size_t)NROWS * 2048 * 2)); // yb aliases
    unsigned short* xdbb = (unsigned short*)(ws + alloc((size_t)NROWS * 96 * 2));

    float* dtp = xz;                 // dt written with stride 4096 over xr region
    float* out_mm = xc;              // out_proj output; xc dead after scan pass C
    unsigned short* yb = xcb;        // bf16 gated y; xcb dead after x_proj
    float* Cp = P;                   // split-K partials (12.6MB) alias P+Q; dead before scan

    // conversions
    cvt_kernel<<<(NROWS * 1024 / 8 + 255) / 256, 256, 0, stream>>>(x, xb, NROWS * 1024 / 8);
    cvt_kernel<<<(4096 * 1024 / 8 + 255) / 256, 256, 0, stream>>>(w1, w1b, 4096 * 1024 / 8);
    cvt_kernel<<<(96 * 2048 / 8 + 255) / 256, 256, 0, stream>>>(xpw, xpwb, 96 * 2048 / 8);
    cvt_kernel<<<(2048 * 64 / 8 + 255) / 256, 256, 0, stream>>>(dtw, dtwb, 2048 * 64 / 8);
    cvt_kernel<<<(1024 * 2048 / 8 + 255) / 256, 256, 0, stream>>>(w4, w4b, 1024 * 2048 / 8);

    // in_proj: xz[4096,4096] = xb[4096,1024] @ w1b[4096,1024]^T
    gemm_gl_kernel<0><<<dim3(32, 32), 256, 0, stream>>>(xb, 1024, w1b, 1024, xz, 4096,
                                                        NROWS, 4096, 16, nullptr);
    // conv + silu
    conv_silu_kernel<<<NROWS * 2048 / 256, 256, 0, stream>>>(xz, cw, cb, xc, xcb);
    // x_proj split-K x8: Cp[8][4096,96] = xcb @ xpwb^T
    gemm_gl_kernel<0><<<dim3(1, 32, 8), 256, 0, stream>>>(xcb, 2048, xpwb, 2048, Cp, 96,
                                                          NROWS, 96, 4, nullptr);
    xproj_reduce_kernel<<<(NROWS * 96 + 255) / 256, 256, 0, stream>>>(Cp, xdb, xdbb);
    // dt_proj + softplus: dt[4096,2048] (stride 4096, aliases xz xr-half)
    gemm_gl_kernel<1><<<dim3(16, 32), 256, 0, stream>>>(xdbb, 96, dtwb, 64, dtp, 4096,
                                                        NROWS, 2048, 1, dtb);
    // chunked scan
    scan_partial_kernel<<<512, 256, 0, stream>>>(dtp, 4096, xc, xdb, Alog, P, Q);
    scan_combine_kernel<<<16, 256, 0, stream>>>(P, Q, Hs);
    scan_final_kernel<<<512, 256, 0, stream>>>(dtp, 4096, xc, xdb, Alog, Hs, Dp, xz, yb);
    // out_proj: out_mm[4096,1024] = yb @ w4b^T
    gemm_gl_kernel<0><<<dim3(8, 32), 256, 0, stream>>>(yb, 2048, w4b, 2048, out_mm, 1024,
                                                       NROWS, 1024, 32, nullptr);
    // residual + LayerNorm
    ln_kernel<<<NROWS, 256, 0, stream>>>(out_mm, x, lnw, lnb, out);
}